// Round 4
// baseline (877.235 us; speedup 1.0000x reference)
//
#include <hip/hip_runtime.h>
#include <hip/hip_bf16.h>

#define NALGOS 64
#define NTASKS 256
#define TSTEPS 4096
#define CHUNK  256                 // steps per expand block
#define NCHUNK (TSTEPS / CHUNK)    // 16
#define TPT    257                 // expand tile pitch along t (slot 256 = chunk-end col)
#define LOG2E  1.44269504f

// ---------------- Phase 1: driver --------------------------------------------
// r2-exact v3 driver (measured 312 us). Cross-lane select algebraically
// deferred two steps; serial chain is rcp -> fma -> exp2 -> add.
__global__ __launch_bounds__(64) void driver_kernel(
    const int* __restrict__ lx, const float* __restrict__ tmat,
    const float* __restrict__ diff, const float* __restrict__ eff_v,
    const float* __restrict__ mem_v, const float* __restrict__ boost_v,
    float* __restrict__ g_arr, float* __restrict__ ckpt) {
  __shared__ int    lx_s[TSTEPS + 16];
  __shared__ float  c_s[NTASKS];
  __shared__ float4 ctab[TSTEPS + 8];   // {X, Y, Z, E}
  __shared__ int    itab[TSTEPS + 8];   // lx[i+3] | lx[i+8]<<16

  const int a = blockIdx.x;
  const int l = threadIdx.x;
  const float eff   = eff_v[a];
  const float mem   = mem_v[a];
  const float boost = boost_v[a];
  const float e0 = eff - boost;
  const float b2 = 2.0f * boost;
  const float m2 = mem * mem;

#pragma unroll 8
  for (int k = 0; k < TSTEPS / 64; ++k) lx_s[k * 64 + l] = lx[k * 64 + l];
  if (l < 16) lx_s[TSTEPS + l] = 0;
#pragma unroll
  for (int k = 0; k < NTASKS / 64; ++k) {
    float dk = diff[k * 64 + l];
    c_s[k * 64 + l] = -LOG2E / dk;
  }
  __syncthreads();

#pragma unroll 4
  for (int k = 0; k < TSTEPS / 64; ++k) {
    int i  = k * 64 + l;
    int t1 = lx_s[i + 1];
    float q  = tmat[lx_s[i] * NTASKS + t1];
    float q2 = (i >= 1) ? tmat[lx_s[i - 1] * NTASKS + t1] : 0.f;
    float cp = c_s[t1];
    float4 e;
    e.x = b2 * cp * q;                        // X_i
    e.y = b2 * cp * mem * q2;                 // Y_i
    e.z = e0 * cp * (q + mem * q2);           // Z_i
    e.w = cp * m2;                            // E_i
    ctab[i] = e;
    itab[i] = lx_s[i + 3] | (lx_s[i + 8] << 16);
  }
  if (l < 8) {
    ctab[TSTEPS + l] = make_float4(0.f, 0.f, 0.f, 0.f);
    itab[TSTEPS + l] = 0;
  }
  __syncthreads();

  const float4* rows = (const float4*)tmat;  // row r: rows[r*64 + l]
  float* gout = g_arr + (size_t)a * TSTEPS;
  float* ck   = ckpt  + (size_t)a * NCHUNK * NTASKS;

  float r0 = 0.f, r1 = 0.f, r2 = 0.f, r3 = 0.f;
  float u = 2.0f;                 // 1 + exp2(0): W[0] = 0.5
  float keep_g = 0.f;

  float4 ctr[4];
  int    itr[4];
  float4 tmr[8];
#pragma unroll
  for (int k = 0; k < 4; ++k) { ctr[k] = ctab[k]; itr[k] = itab[k]; }
#pragma unroll
  for (int k = 0; k < 8; ++k) tmr[k] = rows[lx_s[k] * 64 + l];
  float A    = ctr[0].z;          // A_0 = Z_0  (entry 0 built with q2 = 0)
  float base = ctr[1].z;          // base_1 = Z_1  (res_{-1} = 0)

  for (int grp = 0; grp < TSTEPS / 64; ++grp) {
#pragma unroll 1
    for (int k32 = 0; k32 < 2; ++k32) {
      const float4* cb = ctab + grp * 64 + k32 * 32;
      const int*    ib = itab + grp * 64 + k32 * 32;
      const int kb = k32 * 32;
#pragma unroll
      for (int kk = 0; kk < 32; ++kk) {
        const int k = kb + kk;
        const float4 ct0 = ctr[k & 3];         // entry k   (.x = X_k)
        const float4 ct1 = ctr[(k + 1) & 3];   // entry k+1 (.y = Y_{k+1})
        const float4 ct2 = ctr[(k + 2) & 3];   // entry k+2 (.z,.w = Z,E)
        const float4 tm  = tmr[k & 7];         // row lx[k]
        const int    it  = itr[k & 3];

        // ---- critical chain: rcp -> fma -> exp2 -> add ----
        float w   = __builtin_amdgcn_rcpf(u);      // W[k]
        float arg = fmaf(ct0.x, w, A);
        float ev  = __builtin_amdgcn_exp2f(arg);
        u = 1.0f + ev;

        // ---- off-chain ----
        float gt = fmaf(b2, w, e0);                // g_k
        A = fmaf(ct1.y, w, base);                  // A_{k+1}

        keep_g = (k == l) ? gt : keep_g;

        r0 = fmaf(r0, mem, tm.x * gt);
        r1 = fmaf(r1, mem, tm.y * gt);
        r2 = fmaf(r2, mem, tm.z * gt);
        r3 = fmaf(r3, mem, tm.w * gt);

        // select res_k[lx[k+3]] -> base_{k+2}
        const int sw   = __builtin_amdgcn_readfirstlane(it);
        const int j    = sw & 0xff;            // lx[k+3]
        const int lane = j >> 2;
        float h01  = (j & 1) ? r1 : r0;
        float h23  = (j & 1) ? r3 : r2;
        float hsel = (j & 2) ? h23 : h01;
        float bro = __uint_as_float(
            __builtin_amdgcn_readlane(__float_as_uint(hsel), lane));
        base = fmaf(ct2.w, bro, ct2.z);        // base_{k+2}

        // refill pipelines
        ctr[k & 3] = cb[kk + 4];
        itr[k & 3] = ib[kk + 4];
        const int nrow = (sw >> 16) & 0xff;    // lx[k+8]
        tmr[kk & 7] = rows[nrow * 64 + l];
      }
    }
    gout[grp * 64 + l] = keep_g;
    if ((grp & 3) == 3 && grp != 63) {
      float4 s; s.x = r0; s.y = r1; s.z = r2; s.w = r3;
      ((float4*)(ck + ((grp + 1) >> 2) * NTASKS))[l] = s;
    }
  }
}

// ---------------- Phase 2: expand --------------------------------------------
// v5: block = (algo a, 64-column group ng, chunk c); 64 threads, thread = one
// output column n. Tile holds the FULL 256-step chunk per column -> per-row
// store runs are 1 KB (7 full 128B lines + 2 partials, 4x fewer partial lines
// than the old 256B runs => less HBM read-modify-write). tmat loads prefetched
// through a 16-deep register ring (compile-time ring indices). Stores are
// per-lane self-aligned dwordx4 (head/body/tail by the lane's own phase).
// Boundary column t0 = sigma(res_init) uniformly (sigma(0)=0 exactly for c=0).
// XCD swizzle: id = (a*4+ng) + 256*c -> id%8 independent of c, so all 16
// chunks of one (a,ng) land on the same XCD L2.
__global__ __launch_bounds__(64) void expand_kernel(
    const int* __restrict__ lx, const float* __restrict__ tmat,
    const float* __restrict__ diff, const float* __restrict__ mem_v,
    const float* __restrict__ g_arr, const float* __restrict__ ckpt,
    float* __restrict__ out) {
  __shared__ float tile[64 * TPT];    // tile[l*TPT + j]: out col t0+j for col n
  __shared__ int   lx_c[CHUNK + 16];
  __shared__ float g_c[CHUNK];

  const int id = blockIdx.x;          // 0..4095
  const int c  = id >> 8;             // chunk 0..15
  const int r8 = id & 255;
  const int a  = r8 >> 2;             // algorithm 0..63
  const int ng = r8 & 3;              // column group 0..3
  const int l  = threadIdx.x;         // 0..63
  const int n  = ng * 64 + l;         // output column 0..255

  const float mem = mem_v[a];
  const float cn  = -LOG2E / diff[n];
  const int t0 = c * CHUNK;

  // stage lx / g for this chunk
#pragma unroll
  for (int i = 0; i < 4; ++i) {
    lx_c[i * 64 + l] = lx[t0 + i * 64 + l];
    g_c[i * 64 + l]  = g_arr[(size_t)a * TSTEPS + t0 + i * 64 + l];
  }
  if (l < 16) lx_c[CHUNK + l] = 0;
  __syncthreads();

  float res = (c == 0) ? 0.f : ckpt[((size_t)a * NCHUNK + c) * NTASKS + n];

  // boundary column: sigma(res_init)  (== 0 exactly when c == 0)
  {
    float w = __builtin_amdgcn_rcpf(1.0f + __builtin_amdgcn_exp2f(cn * res));
    tile[l * TPT + 0] = fmaf(2.0f, w, -1.0f);
  }

  // 16-deep tmat prefetch ring
  float tmr[16];
#pragma unroll
  for (int i = 0; i < 16; ++i) tmr[i] = tmat[lx_c[i] * NTASKS + n];

  // 256 steps; step s consumes lx/g at global t0+s, writes tile slot s+1
#pragma unroll 16
  for (int s = 0; s < CHUNK; ++s) {
    float tm = tmr[s & 15];
    res = fmaf(res, mem, tm * g_c[s]);
    float w = __builtin_amdgcn_rcpf(1.0f + __builtin_amdgcn_exp2f(cn * res));
    tile[l * TPT + s + 1] = fmaf(2.0f, w, -1.0f);
    tmr[s & 15] = tmat[lx_c[s + 16] * NTASKS + n];   // prefetch s+16
  }
  __syncthreads();

  // flush: thread l writes its own row (a*256+n), cols [t0, t0+256)
  const float* trow = &tile[l * TPT];
  float* orow = out + ((size_t)a * NTASKS + n) * (size_t)(TSTEPS + 1) + t0;
  const int j0 = (-n) & 3;            // 16B-aligned start phase for this row
  // head dwords
#pragma unroll
  for (int h = 0; h < 3; ++h)
    if (h < j0) orow[h] = trow[h];
  // aligned dwordx4 body
  const int nb = (CHUNK - j0) >> 2;   // 64 (j0==0) or 63
  for (int b = 0; b < nb; ++b) {
    const int col = j0 + 4 * b;
    float4 v = make_float4(trow[col], trow[col + 1], trow[col + 2], trow[col + 3]);
    *reinterpret_cast<float4*>(orow + col) = v;   // 16B-aligned by construction
  }
  // tail dwords
#pragma unroll
  for (int t2 = 0; t2 < 3; ++t2) {
    const int col = j0 + 4 * nb + t2;
    if (col < CHUNK) orow[col] = trow[col];
  }
  // final column of the whole output (only last chunk)
  if (c == NCHUNK - 1) orow[CHUNK] = trow[CHUNK];
}

extern "C" void kernel_launch(void* const* d_in, const int* in_sizes, int n_in,
                              void* d_out, int out_size, void* d_ws, size_t ws_size,
                              hipStream_t stream) {
  const int*   lx    = (const int*)d_in[0];
  const float* tmat  = (const float*)d_in[1];
  const float* diff  = (const float*)d_in[2];
  const float* eff   = (const float*)d_in[3];
  const float* mem   = (const float*)d_in[4];
  const float* boost = (const float*)d_in[5];
  float* out = (float*)d_out;

  float* g_arr = (float*)d_ws;                      // 64*4096 f32 = 1 MB
  float* ckpt  = g_arr + (size_t)NALGOS * TSTEPS;   // 64*16*256 f32 = 1 MB

  driver_kernel<<<NALGOS, 64, 0, stream>>>(lx, tmat, diff, eff, mem, boost,
                                           g_arr, ckpt);
  expand_kernel<<<dim3(NCHUNK * NALGOS * 4), 64, 0, stream>>>(
      lx, tmat, diff, mem, g_arr, ckpt, out);
}